// Round 6
// baseline (509.575 us; speedup 1.0000x reference)
//
#include <hip/hip_runtime.h>
#include <math.h>

#define DD 128          // node embedding dim
#define RR 1024         // root nodes
#define TT 4            // trunk types; encoder TT is the output autoencoder
#define LL 64           // levels
#define MM 2048         // nodes per level
#define NBK 16          // nodes per chunk (one MFMA M-tile)
#define PAD16 (MM + 5*NBK)   // 2128 padded slots per level
#define CH (PAD16/NBK)       // 133 chunks per level == grid of persistent kernel

typedef __attribute__((ext_vector_type(8))) short short8v;   // 8 bf16 (4 VGPRs)
typedef __attribute__((ext_vector_type(4))) float f32x4;

static __device__ __forceinline__ unsigned short f2bf(float f) {
    unsigned u = __float_as_uint(f);
    unsigned r = (u + 0x7fffu + ((u >> 16) & 1u)) >> 16;   // RNE
    return (unsigned short)r;
}

// ---------------------------------------------------------------------------
// Fused prep: [0,64) build order+chunkof | [64,304) convert weights |
// [304,336) copy roots | 336 zero flags.   One dispatch.
// ---------------------------------------------------------------------------
__global__ __launch_bounds__(256) void prep_all(
    const float* __restrict__ root, const float* __restrict__ W1,
    const float* __restrict__ W2, const int* __restrict__ types,
    float* __restrict__ buf,
    unsigned short* __restrict__ W1F, unsigned short* __restrict__ W2F,
    unsigned short* __restrict__ order, unsigned char* __restrict__ chunkof,
    unsigned int* __restrict__ flags)
{
    int bid = blockIdx.x, tid = threadIdx.x;
    if (bid < LL) {
        int l = bid;
        __shared__ int cnt[5], cur[5];
        if (tid < 5) cnt[tid] = 0;
        __syncthreads();
        for (int s = tid; s < PAD16; s += 256) order[l*PAD16 + s] = 0xFFFFu;
        for (int m = tid; m < MM; m += 256) {
            int t = types[l*MM + m];
            int e = (t >= TT) ? TT : t;
            atomicAdd(&cnt[e], 1);
        }
        __syncthreads();
        if (tid == 0) {
            int off = 0;
            for (int e = 0; e < 5; e++) { cur[e] = off; off += ((cnt[e] + NBK - 1)/NBK)*NBK; }
        }
        __syncthreads();
        for (int m = tid; m < MM; m += 256) {
            int t = types[l*MM + m];
            int e = (t >= TT) ? TT : t;
            int pos = atomicAdd(&cur[e], 1);
            order[l*PAD16 + pos] = (unsigned short)m;
            chunkof[l*MM + m] = (unsigned char)(pos >> 4);
        }
    } else if (bid < LL + 240) {
        int t0 = (bid - LL)*256 + tid;
        if (t0 < 5*16*8*64) {
            int lane = t0 & 63;
            int kk = (t0 >> 6) & 7;
            int nt = (t0 >> 9) & 15;
            int e  = t0 >> 13;
            int n  = nt*16 + (lane & 15);
            int k0 = kk*32 + (lane >> 4)*8;
            unsigned short v[8];
            #pragma unroll
            for (int j = 0; j < 8; j++) v[j] = f2bf(W1[(e*256 + k0 + j)*256 + n]);
            *(short8v*)&W1F[t0*8] = *(short8v*)v;
        } else {
            int t = t0 - 5*16*8*64;   // < 20480
            int lane = t & 63;
            int kk = (t >> 6) & 7;
            int nt = (t >> 9) & 7;
            int e  = t >> 12;
            int n  = nt*16 + (lane & 15);
            int k0 = kk*32 + (lane >> 4)*8;
            unsigned short v[8];
            #pragma unroll
            for (int j = 0; j < 8; j++) v[j] = f2bf(W2[(e*256 + k0 + j)*128 + n]);
            *(short8v*)&W2F[t*8] = *(short8v*)v;
        }
    } else if (bid < LL + 240 + 32) {
        int idx = (bid - (LL + 240))*256 + tid;   // 0..8191
        const f32x4* r4 = (const f32x4*)root;
        f32x4* o4 = (f32x4*)buf;
        #pragma unroll
        for (int q = 0; q < 4; q++) o4[idx*4 + q] = r4[idx*4 + q];
    } else {
        for (int i = tid; i < LL*CH; i += 256) flags[i] = 0u;
    }
}

// ---------------------------------------------------------------------------
// Gather helpers: thread (m = tid>>4, seg = tid&15) owns 16 floats of node m's
// 256-float x. try: load if producer flag ready (or root/slot), else defer.
// ---------------------------------------------------------------------------
struct PendT { const float* src; int fi; bool on; };

static __device__ __forceinline__ void load16(const float* src, float* vals) {
    const unsigned long long* s8 = (const unsigned long long*)src;
    #pragma unroll
    for (int q = 0; q < 8; q++) {
        unsigned long long u = __hip_atomic_load(&s8[q], __ATOMIC_RELAXED,
                                                 __HIP_MEMORY_SCOPE_AGENT);
        vals[2*q+0] = __uint_as_float((unsigned)(u & 0xFFFFFFFFull));
        vals[2*q+1] = __uint_as_float((unsigned)(u >> 32));
    }
}

static __device__ __forceinline__ void write_frags(unsigned short* axT, int m,
                                                   int seg, const float* vals) {
    #pragma unroll
    for (int h = 0; h < 2; h++) {
        int k = seg*16 + h*8;
        int kk = k >> 5;
        int lane = m + 16*((k >> 3) & 3);
        unsigned short tmp[8];
        #pragma unroll
        for (int j = 0; j < 8; j++) tmp[j] = f2bf(vals[h*8 + j]);
        *(short8v*)&axT[(kk*64 + lane)*8] = *(short8v*)tmp;
    }
}

static __device__ __forceinline__ PendT gather_try(
    int tid, const int4* descL, const int2* desc2L,
    const float* __restrict__ buf, const float* __restrict__ slots,
    const unsigned int* __restrict__ flags, unsigned short* axT)
{
    PendT P; P.on = false; P.src = nullptr; P.fi = 0;
    int m = tid >> 4, seg = tid & 15;
    int4 d = descL[m];
    float vals[16];
    if (d.x >= 0) {
        int2 d2 = desc2L[m];
        const float* src; int fi;
        if (seg < 8)      { src = buf   + (size_t)d.y*DD   + seg*16;     fi = d2.x; }
        else if (d.z < 0) { src = slots + (size_t)(~d.z)*DD + (seg-8)*16; fi = -1;  }
        else              { src = buf   + (size_t)d.z*DD   + (seg-8)*16; fi = d2.y; }
        bool ready = (fi < 0) ||
            (__hip_atomic_load(&flags[fi], __ATOMIC_RELAXED, __HIP_MEMORY_SCOPE_AGENT) != 0u);
        if (ready) {
            asm volatile("" ::: "memory");   // no hoisting of data loads above flag check
            load16(src, vals);
            write_frags(axT, m, seg, vals);
        } else {
            P.on = true; P.src = src; P.fi = fi;
        }
    } else {
        #pragma unroll
        for (int q = 0; q < 16; q++) vals[q] = 0.f;
        write_frags(axT, m, seg, vals);
    }
    return P;
}

static __device__ __forceinline__ void gather_patch(
    PendT P, int tid, const unsigned int* __restrict__ flags, unsigned short* axT)
{
    if (!P.on) return;
    while (__hip_atomic_load(&flags[P.fi], __ATOMIC_RELAXED,
                             __HIP_MEMORY_SCOPE_AGENT) == 0u)
        __builtin_amdgcn_s_sleep(1);
    asm volatile("" ::: "memory");           // no hoisting of data loads above flag spin
    float vals[16];
    load16(P.src, vals);
    write_frags(axT, tid >> 4, tid & 15, vals);
}

// ---------------------------------------------------------------------------
// Persistent dataflow kernel: 133 WGs x 256 threads. WG g owns chunk g of every
// level and marches independently; per-(level,chunk) ready flags replace the
// global barrier. Result rows are written with RETURNING atomic swaps: the
// returned value proves the write executed at the L3 coherence point, so
// vmcnt-drain at __syncthreads() + flag store gives airtight data-before-flag.
// ---------------------------------------------------------------------------
__global__ __launch_bounds__(256, 1) void persist_mfma(
    const unsigned short* __restrict__ W1F, const unsigned short* __restrict__ W2F,
    const float* __restrict__ b1, const float* __restrict__ b2,
    const float* __restrict__ slots, const int* __restrict__ par,
    const int* __restrict__ types, const unsigned short* __restrict__ order,
    const unsigned char* __restrict__ chunkof,
    float* __restrict__ buf, unsigned int* __restrict__ flags)
{
    __shared__ int4 descs[LL][NBK];            // {node, p0, p1(~slot if out), etype}
    __shared__ int2 descs2[LL][NBK];           // producer flag idx per parent (-1 ready)
    __shared__ int ech[LL];
    __shared__ unsigned short axFA[8*64*8];    // A-frags of x, 8 KB
    __shared__ unsigned short axFB[8*64*8];    // double buffer, 8 KB
    __shared__ unsigned short hxF[8*64*8];     // A-frags of h, 8 KB

    int tid = threadIdx.x;
    int wg  = blockIdx.x;

    // ---- prologue: resolve all levels' descriptors + producer flags ----
    for (int i = tid; i < LL*NBK; i += 256) {
        int l = i >> 4, s = i & 15;
        unsigned short o = order[l*PAD16 + wg*NBK + s];
        int4 d; int2 d2 = make_int2(-1, -1);
        if (o == 0xFFFFu) {
            d = make_int4(-1, 0, 0, -1);
        } else {
            int gi = l*MM + (int)o;
            int t = types[gi];
            int e = (t >= TT) ? TT : t;
            int p0 = par[2*gi];
            int p1 = (t >= TT) ? ~(t - TT) : par[2*gi + 1];
            d = make_int4((int)o, p0, p1, e);
            if (p0 >= RR) d2.x = ((p0 - RR) >> 11)*CH + (int)chunkof[p0 - RR];
            if (p1 >= RR) d2.y = ((p1 - RR) >> 11)*CH + (int)chunkof[p1 - RR];
        }
        descs[l][s] = d;
        descs2[l][s] = d2;
    }
    __syncthreads();
    for (int i = tid; i < LL; i += 256) ech[i] = descs[i][0].w;
    __syncthreads();

    int w  = tid >> 6;    // wave 0..3
    int lq = tid & 63;    // lane

    // ---- level 0 gather (all parents are roots/slots: always ready) ----
    {
        PendT P = gather_try(tid, descs[0], descs2[0], buf, slots, flags, axFA);
        gather_patch(P, tid, flags, axFA);
    }
    __syncthreads();

    unsigned short* axc = axFA;
    unsigned short* axn = axFB;

    for (int l = 0; l < LL; l++) {
        int e = ech[l];
        if (e >= 0) {
            // ---- layer 1: H = GELU(X @ W1[e] + b1[e]) ----
            f32x4 acc[4];
            #pragma unroll
            for (int c = 0; c < 4; c++) {
                float bv = b1[e*256 + w*64 + c*16 + (lq & 15)];
                acc[c] = (f32x4){bv, bv, bv, bv};
            }
            {
                const short8v* Ab = (const short8v*)axc;
                #pragma unroll
                for (int kk = 0; kk < 8; kk++) {
                    short8v a = Ab[kk*64 + lq];
                    #pragma unroll
                    for (int c = 0; c < 4; c++) {
                        int nt = w*4 + c;
                        short8v bfr = *(const short8v*)&W1F[(((e*16 + nt)*8 + kk)*64 + lq)*8];
                        acc[c] = __builtin_amdgcn_mfma_f32_16x16x32_bf16(a, bfr, acc[c], 0, 0, 0);
                    }
                }
            }
            #pragma unroll
            for (int c = 0; c < 4; c++) {
                int nh = w*64 + c*16 + (lq & 15);
                int kk2 = nh >> 5;
                int jj  = nh & 7;
                int lhi = 16*((nh >> 3) & 3);
                #pragma unroll
                for (int r = 0; r < 4; r++) {
                    int m = (lq >> 4)*4 + r;
                    float h = acc[c][r];
                    float gg = 0.5f*h*(1.0f + erff(h*0.70710678118654752f));
                    hxF[(kk2*64 + (m + lhi))*8 + jj] = f2bf(gg);
                }
            }
            __syncthreads();

            // ---- layer 2: OUT = H @ W2[e] + b2[e] ----
            f32x4 acc2[2];
            #pragma unroll
            for (int c = 0; c < 2; c++) {
                float bv = b2[e*128 + w*32 + c*16 + (lq & 15)];
                acc2[c] = (f32x4){bv, bv, bv, bv};
            }
            {
                const short8v* Hb = (const short8v*)hxF;
                #pragma unroll
                for (int kk = 0; kk < 8; kk++) {
                    short8v a = Hb[kk*64 + lq];
                    #pragma unroll
                    for (int c = 0; c < 2; c++) {
                        int nt = w*2 + c;
                        short8v bfr = *(const short8v*)&W2F[(((e*8 + nt)*8 + kk)*64 + lq)*8];
                        acc2[c] = __builtin_amdgcn_mfma_f32_16x16x32_bf16(a, bfr, acc2[c], 0, 0, 0);
                    }
                }
            }
            // result rows: RETURNING atomic swap -> executes at L3 slice; keep the
            // returned value alive so the round trip can't be optimized away.
            int baserow = RR + l*MM;
            unsigned dummy = 0;
            #pragma unroll
            for (int r = 0; r < 4; r++) {
                int m = (lq >> 4)*4 + r;
                int node = descs[l][m].x;
                if (node >= 0) {
                    #pragma unroll
                    for (int c = 0; c < 2; c++) {
                        int n = w*32 + c*16 + (lq & 15);
                        unsigned* p = (unsigned*)&buf[(size_t)(baserow + node)*DD + n];
                        unsigned old = __hip_atomic_exchange(p, __float_as_uint(acc2[c][r]),
                                                             __ATOMIC_RELAXED,
                                                             __HIP_MEMORY_SCOPE_AGENT);
                        dummy += old;
                    }
                }
            }
            asm volatile("" :: "v"(dummy));   // liveness: forces the returning swaps
        }
        // all waves' swaps retired (vmcnt(0) at barrier) => data at coherence point
        __syncthreads();
        // publish this (level, chunk)
        if (e >= 0 && tid == 0)
            __hip_atomic_store(&flags[l*CH + wg], 1u, __ATOMIC_RELAXED,
                               __HIP_MEMORY_SCOPE_AGENT);
        // prefetch next level into the other buffer; spin only on missing deps
        if (l + 1 < LL && ech[l+1] >= 0) {
            PendT P = gather_try(tid, descs[l+1], descs2[l+1], buf, slots, flags, axn);
            gather_patch(P, tid, flags, axn);
        }
        __syncthreads();
        unsigned short* t2 = axc; axc = axn; axn = t2;
    }
}

extern "C" void kernel_launch(void* const* d_in, const int* in_sizes, int n_in,
                              void* d_out, int out_size, void* d_ws, size_t ws_size,
                              hipStream_t stream) {
    const float* root  = (const float*)d_in[0];   // (1024, 128)
    const float* W1    = (const float*)d_in[1];   // (5, 256, 256)
    const float* b1    = (const float*)d_in[2];   // (5, 256)
    const float* W2    = (const float*)d_in[3];   // (5, 256, 128)
    const float* b2    = (const float*)d_in[4];   // (5, 128)
    const float* slots = (const float*)d_in[5];   // (256, 128)
    const int*   par   = (const int*)d_in[6];     // (131072, 2)
    const int*   typ   = (const int*)d_in[7];     // (131072,)
    float* out = (float*)d_out;                   // (132096, 128)

    unsigned short* W1F     = (unsigned short*)d_ws;          // 327680 shorts
    unsigned short* W2F     = W1F + 5*16*8*64*8;              // 163840 shorts
    unsigned short* order   = W2F + 5*8*8*64*8;               // 64*2128 shorts
    unsigned char*  chunkof = (unsigned char*)(order + LL*PAD16);  // 131072 B
    unsigned int*   flags   = (unsigned int*)(chunkof + LL*MM);    // 8512 u32

    // single fused prep dispatch (order/chunkof, weights, roots, flags)
    prep_all<<<LL + 240 + 32 + 1, 256, 0, stream>>>(root, W1, W2, typ, out,
                                                    W1F, W2F, order, chunkof, flags);

    // persistent dataflow sweep (co-residency guaranteed by cooperative launch)
    void* args[] = { (void*)&W1F, (void*)&W2F, (void*)&b1, (void*)&b2,
                     (void*)&slots, (void*)&par, (void*)&typ, (void*)&order,
                     (void*)&chunkof, (void*)&out, (void*)&flags };
    hipLaunchCooperativeKernel((const void*)persist_mfma, dim3(CH), dim3(256),
                               args, 0, stream);
}

// Round 7
// 449.029 us; speedup vs baseline: 1.1348x; 1.1348x over previous
//
#include <hip/hip_runtime.h>
#include <math.h>

#define DD 128          // node embedding dim
#define RR 1024         // root nodes
#define TT 4            // trunk types; encoder TT is the output autoencoder
#define LL 64           // levels
#define MM 2048         // nodes per level
#define NBK 16          // nodes per chunk (one MFMA M-tile)
#define PAD16 (MM + 5*NBK)   // 2128 padded slots per level
#define CH (PAD16/NBK)       // 133 chunks per level == grid of persistent kernel

typedef __attribute__((ext_vector_type(8))) short short8v;   // 8 bf16 (4 VGPRs)
typedef __attribute__((ext_vector_type(4))) float f32x4;

static __device__ __forceinline__ unsigned short f2bf(float f) {
    unsigned u = __float_as_uint(f);
    unsigned r = (u + 0x7fffu + ((u >> 16) & 1u)) >> 16;   // RNE
    return (unsigned short)r;
}

// ---------------------------------------------------------------------------
// Fused prep: [0,64) build order+chunkof | [64,304) convert weights |
// [304,336) copy roots | 336 zero flags.   One dispatch.
// ---------------------------------------------------------------------------
__global__ __launch_bounds__(256) void prep_all(
    const float* __restrict__ root, const float* __restrict__ W1,
    const float* __restrict__ W2, const int* __restrict__ types,
    float* __restrict__ buf,
    unsigned short* __restrict__ W1F, unsigned short* __restrict__ W2F,
    unsigned short* __restrict__ order, unsigned char* __restrict__ chunkof,
    unsigned int* __restrict__ flags)
{
    int bid = blockIdx.x, tid = threadIdx.x;
    if (bid < LL) {
        int l = bid;
        __shared__ int cnt[5], cur[5];
        if (tid < 5) cnt[tid] = 0;
        __syncthreads();
        for (int s = tid; s < PAD16; s += 256) order[l*PAD16 + s] = 0xFFFFu;
        for (int m = tid; m < MM; m += 256) {
            int t = types[l*MM + m];
            int e = (t >= TT) ? TT : t;
            atomicAdd(&cnt[e], 1);
        }
        __syncthreads();
        if (tid == 0) {
            int off = 0;
            for (int e = 0; e < 5; e++) { cur[e] = off; off += ((cnt[e] + NBK - 1)/NBK)*NBK; }
        }
        __syncthreads();
        for (int m = tid; m < MM; m += 256) {
            int t = types[l*MM + m];
            int e = (t >= TT) ? TT : t;
            int pos = atomicAdd(&cur[e], 1);
            order[l*PAD16 + pos] = (unsigned short)m;
            chunkof[l*MM + m] = (unsigned char)(pos >> 4);
        }
    } else if (bid < LL + 240) {
        int t0 = (bid - LL)*256 + tid;
        if (t0 < 5*16*8*64) {
            int lane = t0 & 63;
            int kk = (t0 >> 6) & 7;
            int nt = (t0 >> 9) & 15;
            int e  = t0 >> 13;
            int n  = nt*16 + (lane & 15);
            int k0 = kk*32 + (lane >> 4)*8;
            unsigned short v[8];
            #pragma unroll
            for (int j = 0; j < 8; j++) v[j] = f2bf(W1[(e*256 + k0 + j)*256 + n]);
            *(short8v*)&W1F[t0*8] = *(short8v*)v;
        } else {
            int t = t0 - 5*16*8*64;   // < 20480
            int lane = t & 63;
            int kk = (t >> 6) & 7;
            int nt = (t >> 9) & 7;
            int e  = t >> 12;
            int n  = nt*16 + (lane & 15);
            int k0 = kk*32 + (lane >> 4)*8;
            unsigned short v[8];
            #pragma unroll
            for (int j = 0; j < 8; j++) v[j] = f2bf(W2[(e*256 + k0 + j)*128 + n]);
            *(short8v*)&W2F[t*8] = *(short8v*)v;
        }
    } else if (bid < LL + 240 + 32) {
        int idx = (bid - (LL + 240))*256 + tid;   // 0..8191
        const f32x4* r4 = (const f32x4*)root;
        f32x4* o4 = (f32x4*)buf;
        #pragma unroll
        for (int q = 0; q < 4; q++) o4[idx*4 + q] = r4[idx*4 + q];
    } else {
        for (int i = tid; i < LL*CH; i += 256) flags[i] = 0u;
    }
}

// ---------------------------------------------------------------------------
// Gather helpers: thread (m = tid>>4, seg = tid&15) owns 16 floats of node m's
// 256-float x. try: load if producer flag ready (or root/slot), else defer.
// ---------------------------------------------------------------------------
struct PendT { const float* src; int fi; bool on; };

static __device__ __forceinline__ void load16(const float* src, float* vals) {
    const unsigned long long* s8 = (const unsigned long long*)src;
    #pragma unroll
    for (int q = 0; q < 8; q++) {
        unsigned long long u = __hip_atomic_load(&s8[q], __ATOMIC_RELAXED,
                                                 __HIP_MEMORY_SCOPE_AGENT);
        vals[2*q+0] = __uint_as_float((unsigned)(u & 0xFFFFFFFFull));
        vals[2*q+1] = __uint_as_float((unsigned)(u >> 32));
    }
}

static __device__ __forceinline__ void write_frags(unsigned short* axT, int m,
                                                   int seg, const float* vals) {
    #pragma unroll
    for (int h = 0; h < 2; h++) {
        int k = seg*16 + h*8;
        int kk = k >> 5;
        int lane = m + 16*((k >> 3) & 3);
        unsigned short tmp[8];
        #pragma unroll
        for (int j = 0; j < 8; j++) tmp[j] = f2bf(vals[h*8 + j]);
        *(short8v*)&axT[(kk*64 + lane)*8] = *(short8v*)tmp;
    }
}

static __device__ __forceinline__ PendT gather_try(
    int tid, const int4* descL, const int2* desc2L,
    const float* __restrict__ buf, const float* __restrict__ slots,
    const unsigned int* __restrict__ flags, unsigned short* axT)
{
    PendT P; P.on = false; P.src = nullptr; P.fi = 0;
    int m = tid >> 4, seg = tid & 15;
    int4 d = descL[m];
    float vals[16];
    if (d.x >= 0) {
        int2 d2 = desc2L[m];
        const float* src; int fi;
        if (seg < 8)      { src = buf   + (size_t)d.y*DD   + seg*16;     fi = d2.x; }
        else if (d.z < 0) { src = slots + (size_t)(~d.z)*DD + (seg-8)*16; fi = -1;  }
        else              { src = buf   + (size_t)d.z*DD   + (seg-8)*16; fi = d2.y; }
        bool ready = (fi < 0) ||
            (__hip_atomic_load(&flags[fi], __ATOMIC_RELAXED, __HIP_MEMORY_SCOPE_AGENT) != 0u);
        if (ready) {
            asm volatile("" ::: "memory");   // no hoisting of data loads above flag check
            load16(src, vals);
            write_frags(axT, m, seg, vals);
        } else {
            P.on = true; P.src = src; P.fi = fi;
        }
    } else {
        #pragma unroll
        for (int q = 0; q < 16; q++) vals[q] = 0.f;
        write_frags(axT, m, seg, vals);
    }
    return P;
}

static __device__ __forceinline__ void gather_patch(
    PendT P, int tid, const unsigned int* __restrict__ flags, unsigned short* axT)
{
    if (!P.on) return;
    while (__hip_atomic_load(&flags[P.fi], __ATOMIC_RELAXED,
                             __HIP_MEMORY_SCOPE_AGENT) == 0u)
        __builtin_amdgcn_s_sleep(4);         // ~256cy backoff: 4x less L3 poll traffic
    asm volatile("" ::: "memory");           // no hoisting of data loads above flag spin
    float vals[16];
    load16(P.src, vals);
    write_frags(axT, tid >> 4, tid & 15, vals);
}

// ---------------------------------------------------------------------------
// Persistent dataflow kernel: 133 WGs x 256 threads. WG g owns chunk g of every
// level and marches independently; per-(level,chunk) ready flags replace the
// global barrier. Producer ordering: all result stores are sc1 (L2-bypass,
// coherence-point write-through); each thread drains vmcnt(0), then the WG
// barrier, then the sc1 flag store -- the LLVM agent-release pattern.
// ---------------------------------------------------------------------------
__global__ __launch_bounds__(256, 1) void persist_mfma(
    const unsigned short* __restrict__ W1F, const unsigned short* __restrict__ W2F,
    const float* __restrict__ b1, const float* __restrict__ b2,
    const float* __restrict__ slots, const int* __restrict__ par,
    const int* __restrict__ types, const unsigned short* __restrict__ order,
    const unsigned char* __restrict__ chunkof,
    float* __restrict__ buf, unsigned int* __restrict__ flags)
{
    __shared__ int4 descs[LL][NBK];            // {node, p0, p1(~slot if out), etype}
    __shared__ int2 descs2[LL][NBK];           // producer flag idx per parent (-1 ready)
    __shared__ int ech[LL];
    __shared__ unsigned short axFA[8*64*8];    // A-frags of x, 8 KB
    __shared__ unsigned short axFB[8*64*8];    // double buffer, 8 KB
    __shared__ unsigned short hxF[8*64*8];     // A-frags of h, 8 KB

    int tid = threadIdx.x;
    int wg  = blockIdx.x;

    // ---- prologue: resolve all levels' descriptors + producer flags ----
    for (int i = tid; i < LL*NBK; i += 256) {
        int l = i >> 4, s = i & 15;
        unsigned short o = order[l*PAD16 + wg*NBK + s];
        int4 d; int2 d2 = make_int2(-1, -1);
        if (o == 0xFFFFu) {
            d = make_int4(-1, 0, 0, -1);
        } else {
            int gi = l*MM + (int)o;
            int t = types[gi];
            int e = (t >= TT) ? TT : t;
            int p0 = par[2*gi];
            int p1 = (t >= TT) ? ~(t - TT) : par[2*gi + 1];
            d = make_int4((int)o, p0, p1, e);
            if (p0 >= RR) d2.x = ((p0 - RR) >> 11)*CH + (int)chunkof[p0 - RR];
            if (p1 >= RR) d2.y = ((p1 - RR) >> 11)*CH + (int)chunkof[p1 - RR];
        }
        descs[l][s] = d;
        descs2[l][s] = d2;
    }
    __syncthreads();
    for (int i = tid; i < LL; i += 256) ech[i] = descs[i][0].w;
    __syncthreads();

    int w  = tid >> 6;    // wave 0..3
    int lq = tid & 63;    // lane

    // ---- level 0 gather (all parents are roots/slots: always ready) ----
    {
        PendT P = gather_try(tid, descs[0], descs2[0], buf, slots, flags, axFA);
        gather_patch(P, tid, flags, axFA);
    }
    __syncthreads();

    unsigned short* axc = axFA;
    unsigned short* axn = axFB;

    for (int l = 0; l < LL; l++) {
        int e = ech[l];
        if (e >= 0) {
            // ---- layer 1: H = GELU(X @ W1[e] + b1[e]) ----
            f32x4 acc[4];
            #pragma unroll
            for (int c = 0; c < 4; c++) {
                float bv = b1[e*256 + w*64 + c*16 + (lq & 15)];
                acc[c] = (f32x4){bv, bv, bv, bv};
            }
            {
                const short8v* Ab = (const short8v*)axc;
                #pragma unroll
                for (int kk = 0; kk < 8; kk++) {
                    short8v a = Ab[kk*64 + lq];
                    #pragma unroll
                    for (int c = 0; c < 4; c++) {
                        int nt = w*4 + c;
                        short8v bfr = *(const short8v*)&W1F[(((e*16 + nt)*8 + kk)*64 + lq)*8];
                        acc[c] = __builtin_amdgcn_mfma_f32_16x16x32_bf16(a, bfr, acc[c], 0, 0, 0);
                    }
                }
            }
            #pragma unroll
            for (int c = 0; c < 4; c++) {
                int nh = w*64 + c*16 + (lq & 15);
                int kk2 = nh >> 5;
                int jj  = nh & 7;
                int lhi = 16*((nh >> 3) & 3);
                #pragma unroll
                for (int r = 0; r < 4; r++) {
                    int m = (lq >> 4)*4 + r;
                    float h = acc[c][r];
                    float gg = 0.5f*h*(1.0f + erff(h*0.70710678118654752f));
                    hxF[(kk2*64 + (m + lhi))*8 + jj] = f2bf(gg);
                }
            }
            __syncthreads();

            // ---- layer 2: OUT = H @ W2[e] + b2[e] ----
            f32x4 acc2[2];
            #pragma unroll
            for (int c = 0; c < 2; c++) {
                float bv = b2[e*128 + w*32 + c*16 + (lq & 15)];
                acc2[c] = (f32x4){bv, bv, bv, bv};
            }
            {
                const short8v* Hb = (const short8v*)hxF;
                #pragma unroll
                for (int kk = 0; kk < 8; kk++) {
                    short8v a = Hb[kk*64 + lq];
                    #pragma unroll
                    for (int c = 0; c < 2; c++) {
                        int nt = w*2 + c;
                        short8v bfr = *(const short8v*)&W2F[(((e*8 + nt)*8 + kk)*64 + lq)*8];
                        acc2[c] = __builtin_amdgcn_mfma_f32_16x16x32_bf16(a, bfr, acc2[c], 0, 0, 0);
                    }
                }
            }
            // result rows: plain relaxed agent (sc1) stores -- write-through to the
            // coherence point; fire-and-forget, drained below.
            int baserow = RR + l*MM;
            #pragma unroll
            for (int r = 0; r < 4; r++) {
                int m = (lq >> 4)*4 + r;
                int node = descs[l][m].x;
                if (node >= 0) {
                    #pragma unroll
                    for (int c = 0; c < 2; c++) {
                        int n = w*32 + c*16 + (lq & 15);
                        __hip_atomic_store(&buf[(size_t)(baserow + node)*DD + n], acc2[c][r],
                                           __ATOMIC_RELAXED, __HIP_MEMORY_SCOPE_AGENT);
                    }
                }
            }
            // explicit per-thread drain: sc1 store retire => at coherence point
            asm volatile("s_waitcnt vmcnt(0)" ::: "memory");
        }
        // all waves drained their sc1 stores before the flag store below
        __syncthreads();
        // publish this (level, chunk)
        if (e >= 0 && tid == 0)
            __hip_atomic_store(&flags[l*CH + wg], 1u, __ATOMIC_RELAXED,
                               __HIP_MEMORY_SCOPE_AGENT);
        // prefetch next level into the other buffer; spin only on missing deps
        if (l + 1 < LL && ech[l+1] >= 0) {
            PendT P = gather_try(tid, descs[l+1], descs2[l+1], buf, slots, flags, axn);
            gather_patch(P, tid, flags, axn);
        }
        __syncthreads();
        unsigned short* t2 = axc; axc = axn; axn = t2;
    }
}

extern "C" void kernel_launch(void* const* d_in, const int* in_sizes, int n_in,
                              void* d_out, int out_size, void* d_ws, size_t ws_size,
                              hipStream_t stream) {
    const float* root  = (const float*)d_in[0];   // (1024, 128)
    const float* W1    = (const float*)d_in[1];   // (5, 256, 256)
    const float* b1    = (const float*)d_in[2];   // (5, 256)
    const float* W2    = (const float*)d_in[3];   // (5, 256, 128)
    const float* b2    = (const float*)d_in[4];   // (5, 128)
    const float* slots = (const float*)d_in[5];   // (256, 128)
    const int*   par   = (const int*)d_in[6];     // (131072, 2)
    const int*   typ   = (const int*)d_in[7];     // (131072,)
    float* out = (float*)d_out;                   // (132096, 128)

    unsigned short* W1F     = (unsigned short*)d_ws;          // 327680 shorts
    unsigned short* W2F     = W1F + 5*16*8*64*8;              // 163840 shorts
    unsigned short* order   = W2F + 5*8*8*64*8;               // 64*2128 shorts
    unsigned char*  chunkof = (unsigned char*)(order + LL*PAD16);  // 131072 B
    unsigned int*   flags   = (unsigned int*)(chunkof + LL*MM);    // 8512 u32

    // single fused prep dispatch (order/chunkof, weights, roots, flags)
    prep_all<<<LL + 240 + 32 + 1, 256, 0, stream>>>(root, W1, W2, typ, out,
                                                    W1F, W2F, order, chunkof, flags);

    // persistent dataflow sweep (co-residency guaranteed by cooperative launch)
    void* args[] = { (void*)&W1F, (void*)&W2F, (void*)&b1, (void*)&b2,
                     (void*)&slots, (void*)&par, (void*)&typ, (void*)&order,
                     (void*)&chunkof, (void*)&out, (void*)&flags };
    hipLaunchCooperativeKernel((const void*)persist_mfma, dim3(CH), dim3(256),
                               args, 0, stream);
}

// Round 8
// 436.626 us; speedup vs baseline: 1.1671x; 1.0284x over previous
//
#include <hip/hip_runtime.h>
#include <math.h>

#define DD 128          // node embedding dim
#define RR 1024         // root nodes
#define TT 4            // trunk types; encoder TT is the output autoencoder
#define LL 64           // levels
#define MM 2048         // nodes per level
#define NBK 16          // nodes per chunk (one MFMA M-tile)
#define PAD16 (MM + 5*NBK)   // 2128 padded slots per level
#define CH (PAD16/NBK)       // 133 chunks per level == grid of persistent kernel

typedef __attribute__((ext_vector_type(8))) short short8v;   // 8 bf16 (4 VGPRs)
typedef __attribute__((ext_vector_type(4))) float f32x4;

static __device__ __forceinline__ unsigned short f2bf(float f) {
    unsigned u = __float_as_uint(f);
    unsigned r = (u + 0x7fffu + ((u >> 16) & 1u)) >> 16;   // RNE
    return (unsigned short)r;
}

// ---------------------------------------------------------------------------
// Fused prep: [0,64) build order+chunkof | [64,304) convert weights |
// [304,336) copy roots | 336 zero flags.   One dispatch.
// ---------------------------------------------------------------------------
__global__ __launch_bounds__(256) void prep_all(
    const float* __restrict__ root, const float* __restrict__ W1,
    const float* __restrict__ W2, const int* __restrict__ types,
    float* __restrict__ buf,
    unsigned short* __restrict__ W1F, unsigned short* __restrict__ W2F,
    unsigned short* __restrict__ order, unsigned char* __restrict__ chunkof,
    unsigned int* __restrict__ flags)
{
    int bid = blockIdx.x, tid = threadIdx.x;
    if (bid < LL) {
        int l = bid;
        __shared__ int cnt[5], cur[5];
        if (tid < 5) cnt[tid] = 0;
        __syncthreads();
        for (int s = tid; s < PAD16; s += 256) order[l*PAD16 + s] = 0xFFFFu;
        for (int m = tid; m < MM; m += 256) {
            int t = types[l*MM + m];
            int e = (t >= TT) ? TT : t;
            atomicAdd(&cnt[e], 1);
        }
        __syncthreads();
        if (tid == 0) {
            int off = 0;
            for (int e = 0; e < 5; e++) { cur[e] = off; off += ((cnt[e] + NBK - 1)/NBK)*NBK; }
        }
        __syncthreads();
        for (int m = tid; m < MM; m += 256) {
            int t = types[l*MM + m];
            int e = (t >= TT) ? TT : t;
            int pos = atomicAdd(&cur[e], 1);
            order[l*PAD16 + pos] = (unsigned short)m;
            chunkof[l*MM + m] = (unsigned char)(pos >> 4);
        }
    } else if (bid < LL + 240) {
        int t0 = (bid - LL)*256 + tid;
        if (t0 < 5*16*8*64) {
            int lane = t0 & 63;
            int kk = (t0 >> 6) & 7;
            int nt = (t0 >> 9) & 15;
            int e  = t0 >> 13;
            int n  = nt*16 + (lane & 15);
            int k0 = kk*32 + (lane >> 4)*8;
            unsigned short v[8];
            #pragma unroll
            for (int j = 0; j < 8; j++) v[j] = f2bf(W1[(e*256 + k0 + j)*256 + n]);
            *(short8v*)&W1F[t0*8] = *(short8v*)v;
        } else {
            int t = t0 - 5*16*8*64;   // < 20480
            int lane = t & 63;
            int kk = (t >> 6) & 7;
            int nt = (t >> 9) & 7;
            int e  = t >> 12;
            int n  = nt*16 + (lane & 15);
            int k0 = kk*32 + (lane >> 4)*8;
            unsigned short v[8];
            #pragma unroll
            for (int j = 0; j < 8; j++) v[j] = f2bf(W2[(e*256 + k0 + j)*128 + n]);
            *(short8v*)&W2F[t*8] = *(short8v*)v;
        }
    } else if (bid < LL + 240 + 32) {
        int idx = (bid - (LL + 240))*256 + tid;   // 0..8191
        const f32x4* r4 = (const f32x4*)root;
        f32x4* o4 = (f32x4*)buf;
        #pragma unroll
        for (int q = 0; q < 4; q++) o4[idx*4 + q] = r4[idx*4 + q];
    } else {
        for (int i = tid; i < LL*CH; i += 256) flags[i] = 0u;
    }
}

// ---------------------------------------------------------------------------
// Persistent dataflow kernel: 133 WGs x 256 threads. WG g owns chunk g of every
// level. Pipelined gather: flag values prefetched 2 levels ahead; data loads
// for ready parents issued BEFORE the level's compute (plain cached loads --
// safe because rows are only ever written via sc1, so no L2 can hold a stale
// copy, and dispatch-start acquire invalidated everything). Only flags and
// just-published rows use sc1. Producer protocol unchanged from r7 (passed):
// sc1 stores -> per-thread vmcnt(0) -> barrier -> sc1 flag store.
// ---------------------------------------------------------------------------
__global__ __launch_bounds__(256, 1) void persist_mfma(
    const unsigned short* __restrict__ W1F, const unsigned short* __restrict__ W2F,
    const float* __restrict__ b1, const float* __restrict__ b2,
    const float* __restrict__ slots, const int* __restrict__ par,
    const int* __restrict__ types, const unsigned short* __restrict__ order,
    const unsigned char* __restrict__ chunkof,
    float* __restrict__ buf, unsigned int* __restrict__ flags)
{
    __shared__ int4 descs[LL][NBK];            // {node, p0, p1(~slot if out), etype}
    __shared__ int2 descs2[LL][NBK];           // producer flag idx per parent (-1 ready)
    __shared__ int ech[LL];
    __shared__ unsigned short axFA[8*64*8];    // A-frags of x, 8 KB
    __shared__ unsigned short axFB[8*64*8];    // double buffer, 8 KB
    __shared__ unsigned short hxF[8*64*8];     // A-frags of h, 8 KB

    int tid = threadIdx.x;
    int wg  = blockIdx.x;

    // ---- prologue: resolve all levels' descriptors + producer flags ----
    for (int i = tid; i < LL*NBK; i += 256) {
        int l = i >> 4, s = i & 15;
        unsigned short o = order[l*PAD16 + wg*NBK + s];
        int4 d; int2 d2 = make_int2(-1, -1);
        if (o == 0xFFFFu) {
            d = make_int4(-1, 0, 0, -1);
        } else {
            int gi = l*MM + (int)o;
            int t = types[gi];
            int e = (t >= TT) ? TT : t;
            int p0 = par[2*gi];
            int p1 = (t >= TT) ? ~(t - TT) : par[2*gi + 1];
            d = make_int4((int)o, p0, p1, e);
            if (p0 >= RR) d2.x = ((p0 - RR) >> 11)*CH + (int)chunkof[p0 - RR];
            if (p1 >= RR) d2.y = ((p1 - RR) >> 11)*CH + (int)chunkof[p1 - RR];
        }
        descs[l][s] = d;
        descs2[l][s] = d2;
    }
    __syncthreads();
    for (int i = tid; i < LL; i += 256) ech[i] = descs[i][0].w;
    __syncthreads();

    int w  = tid >> 6;    // wave 0..3
    int lq = tid & 63;    // lane
    int m_own  = tid >> 4;   // row this thread gathers
    int seg_own = tid & 15;  // 16-float segment

    // resolve this thread's source for level l1
    #define RESOLVE(l1, S, F, P) {                                             \
        int4 d_ = descs[l1][m_own];                                            \
        if (d_.x < 0) { P = true; S = nullptr; F = -1; }                       \
        else {                                                                 \
            P = false;                                                         \
            int2 d2_ = descs2[l1][m_own];                                      \
            if (seg_own < 8)  { S = buf + (size_t)d_.y*DD + seg_own*16;  F = d2_.x; } \
            else if (d_.z < 0){ S = slots + (size_t)(~d_.z)*DD + (seg_own-8)*16; F = -1; } \
            else              { S = buf + (size_t)d_.z*DD + (seg_own-8)*16; F = d2_.y; } \
        } }

    // write this thread's 16 gathered floats (v0..v3) as bf16 A-fragments
    #define WRITE_FRAGS(AXT, V0, V1, V2, V3) {                                 \
        unsigned short tA_[8], tB_[8];                                         \
        _Pragma("unroll")                                                      \
        for (int j = 0; j < 4; j++) {                                          \
            tA_[j]   = f2bf(V0[j]); tA_[4+j] = f2bf(V1[j]);                    \
            tB_[j]   = f2bf(V2[j]); tB_[4+j] = f2bf(V3[j]);                    \
        }                                                                      \
        int k_ = seg_own*16;                                                   \
        int kk_ = k_ >> 5, ln_ = m_own + 16*((k_ >> 3) & 3);                   \
        *(short8v*)&AXT[(kk_*64 + ln_)*8] = *(short8v*)tA_;                    \
        k_ += 8; kk_ = k_ >> 5; ln_ = m_own + 16*((k_ >> 3) & 3);              \
        *(short8v*)&AXT[(kk_*64 + ln_)*8] = *(short8v*)tB_;                    \
    }

    // ---- level-0 gather (roots/slots: always ready) ----
    {
        const float* src; int fi; bool pad;
        RESOLVE(0, src, fi, pad);
        f32x4 z = (f32x4){0.f,0.f,0.f,0.f};
        f32x4 v0 = z, v1 = z, v2 = z, v3 = z;
        if (!pad) {
            const f32x4* s4 = (const f32x4*)src;
            v0 = s4[0]; v1 = s4[1]; v2 = s4[2]; v3 = s4[3];
        }
        WRITE_FRAGS(axFA, v0, v1, v2, v3);
    }
    // ---- carry init: flag prefetch for level 1 ----
    const float* srcC = nullptr; int fiC = -1; bool padC = true; unsigned fvC = 1u;
    if (LL > 1) {
        RESOLVE(1, srcC, fiC, padC);
        if (!padC && fiC >= 0)
            fvC = __hip_atomic_load(&flags[fiC], __ATOMIC_RELAXED, __HIP_MEMORY_SCOPE_AGENT);
    }
    __syncthreads();

    unsigned short* axc = axFA;
    unsigned short* axn = axFB;

    for (int l = 0; l < LL; l++) {
        bool havN = (l + 1 < LL);

        // ---- phase A: issue data loads for level l+1 (ready parents) ----
        bool pend = false;
        f32x4 z = (f32x4){0.f,0.f,0.f,0.f};
        f32x4 v0 = z, v1 = z, v2 = z, v3 = z;
        if (havN && !padC) {
            bool ready = (fiC < 0) || (fvC != 0u);
            if (ready) {
                asm volatile("" ::: "memory");   // loads stay after flag branch
                const f32x4* s4 = (const f32x4*)srcC;
                v0 = s4[0]; v1 = s4[1]; v2 = s4[2]; v3 = s4[3];
            } else {
                pend = true;
            }
        }
        // ---- issue flag prefetch for level l+2 (consumed next iteration) ----
        const float* srcN = nullptr; int fiN = -1; bool padN = true; unsigned fvN = 1u;
        if (l + 2 < LL) {
            RESOLVE(l+2, srcN, fiN, padN);
            if (!padN && fiN >= 0)
                fvN = __hip_atomic_load(&flags[fiN], __ATOMIC_RELAXED, __HIP_MEMORY_SCOPE_AGENT);
        }
        __builtin_amdgcn_sched_barrier(0);   // pin: loads issued before compute

        int e = ech[l];
        if (e >= 0) {
            // ---- layer 1: H = GELU(X @ W1[e] + b1[e]) ----
            f32x4 acc[4];
            #pragma unroll
            for (int c = 0; c < 4; c++) {
                float bv = b1[e*256 + w*64 + c*16 + (lq & 15)];
                acc[c] = (f32x4){bv, bv, bv, bv};
            }
            {
                const short8v* Ab = (const short8v*)axc;
                #pragma unroll
                for (int kk = 0; kk < 8; kk++) {
                    short8v a = Ab[kk*64 + lq];
                    #pragma unroll
                    for (int c = 0; c < 4; c++) {
                        int nt = w*4 + c;
                        short8v bfr = *(const short8v*)&W1F[(((e*16 + nt)*8 + kk)*64 + lq)*8];
                        acc[c] = __builtin_amdgcn_mfma_f32_16x16x32_bf16(a, bfr, acc[c], 0, 0, 0);
                    }
                }
            }
            #pragma unroll
            for (int c = 0; c < 4; c++) {
                int nh = w*64 + c*16 + (lq & 15);
                int kk2 = nh >> 5;
                int jj  = nh & 7;
                int lhi = 16*((nh >> 3) & 3);
                #pragma unroll
                for (int r = 0; r < 4; r++) {
                    int m = (lq >> 4)*4 + r;
                    float h = acc[c][r];
                    float gg = 0.5f*h*(1.0f + erff(h*0.70710678118654752f));
                    hxF[(kk2*64 + (m + lhi))*8 + jj] = f2bf(gg);
                }
            }
            __syncthreads();

            // ---- layer 2: OUT = H @ W2[e] + b2[e] ----
            f32x4 acc2[2];
            #pragma unroll
            for (int c = 0; c < 2; c++) {
                float bv = b2[e*128 + w*32 + c*16 + (lq & 15)];
                acc2[c] = (f32x4){bv, bv, bv, bv};
            }
            {
                const short8v* Hb = (const short8v*)hxF;
                #pragma unroll
                for (int kk = 0; kk < 8; kk++) {
                    short8v a = Hb[kk*64 + lq];
                    #pragma unroll
                    for (int c = 0; c < 2; c++) {
                        int nt = w*2 + c;
                        short8v bfr = *(const short8v*)&W2F[(((e*8 + nt)*8 + kk)*64 + lq)*8];
                        acc2[c] = __builtin_amdgcn_mfma_f32_16x16x32_bf16(a, bfr, acc2[c], 0, 0, 0);
                    }
                }
            }
            // result rows: sc1 write-through to the coherence point
            int baserow = RR + l*MM;
            #pragma unroll
            for (int r = 0; r < 4; r++) {
                int m = (lq >> 4)*4 + r;
                int node = descs[l][m].x;
                if (node >= 0) {
                    #pragma unroll
                    for (int c = 0; c < 2; c++) {
                        int n = w*32 + c*16 + (lq & 15);
                        __hip_atomic_store(&buf[(size_t)(baserow + node)*DD + n], acc2[c][r],
                                           __ATOMIC_RELAXED, __HIP_MEMORY_SCOPE_AGENT);
                    }
                }
            }
            // per-thread drain: sc1 store retire => at coherence point
            asm volatile("s_waitcnt vmcnt(0)" ::: "memory");
        }
        __syncthreads();   // all waves drained before flag publish
        if (e >= 0 && tid == 0)
            __hip_atomic_store(&flags[l*CH + wg], 1u, __ATOMIC_RELAXED,
                               __HIP_MEMORY_SCOPE_AGENT);

        // ---- phase B: patch stragglers, convert to next-level fragments ----
        if (havN) {
            if (pend) {
                while (__hip_atomic_load(&flags[fiC], __ATOMIC_RELAXED,
                                         __HIP_MEMORY_SCOPE_AGENT) == 0u)
                    __builtin_amdgcn_s_sleep(2);
                asm volatile("" ::: "memory");
                const f32x4* s4 = (const f32x4*)srcC;
                v0 = s4[0]; v1 = s4[1]; v2 = s4[2]; v3 = s4[3];
            }
            WRITE_FRAGS(axn, v0, v1, v2, v3);
        }
        __syncthreads();
        unsigned short* t2 = axc; axc = axn; axn = t2;
        srcC = srcN; fiC = fiN; padC = padN; fvC = fvN;
    }
}

extern "C" void kernel_launch(void* const* d_in, const int* in_sizes, int n_in,
                              void* d_out, int out_size, void* d_ws, size_t ws_size,
                              hipStream_t stream) {
    const float* root  = (const float*)d_in[0];   // (1024, 128)
    const float* W1    = (const float*)d_in[1];   // (5, 256, 256)
    const float* b1    = (const float*)d_in[2];   // (5, 256)
    const float* W2    = (const float*)d_in[3];   // (5, 256, 128)
    const float* b2    = (const float*)d_in[4];   // (5, 128)
    const float* slots = (const float*)d_in[5];   // (256, 128)
    const int*   par   = (const int*)d_in[6];     // (131072, 2)
    const int*   typ   = (const int*)d_in[7];     // (131072,)
    float* out = (float*)d_out;                   // (132096, 128)

    unsigned short* W1F     = (unsigned short*)d_ws;          // 327680 shorts
    unsigned short* W2F     = W1F + 5*16*8*64*8;              // 163840 shorts
    unsigned short* order   = W2F + 5*8*8*64*8;               // 64*2128 shorts
    unsigned char*  chunkof = (unsigned char*)(order + LL*PAD16);  // 131072 B
    unsigned int*   flags   = (unsigned int*)(chunkof + LL*MM);    // 8512 u32

    // single fused prep dispatch (order/chunkof, weights, roots, flags)
    prep_all<<<LL + 240 + 32 + 1, 256, 0, stream>>>(root, W1, W2, typ, out,
                                                    W1F, W2F, order, chunkof, flags);

    // persistent dataflow sweep (co-residency guaranteed by cooperative launch)
    void* args[] = { (void*)&W1F, (void*)&W2F, (void*)&b1, (void*)&b2,
                     (void*)&slots, (void*)&par, (void*)&typ, (void*)&order,
                     (void*)&chunkof, (void*)&out, (void*)&flags };
    hipLaunchCooperativeKernel((const void*)persist_mfma, dim3(CH), dim3(256),
                               args, 0, stream);
}

// Round 9
// 433.955 us; speedup vs baseline: 1.1743x; 1.0062x over previous
//
#include <hip/hip_runtime.h>
#include <math.h>

#define DD 128          // node embedding dim
#define RR 1024         // root nodes
#define TT 4            // trunk types; encoder TT is the output autoencoder
#define LL 64           // levels
#define MM 2048         // nodes per level
#define NBK 16          // nodes per chunk (one MFMA M-tile)
#define PAD16 (MM + 5*NBK)   // 2128 padded slots per level
#define CH (PAD16/NBK)       // 133 chunks per level == grid of persistent kernel

typedef __attribute__((ext_vector_type(8))) short short8v;   // 8 bf16 (4 VGPRs)
typedef __attribute__((ext_vector_type(4))) float f32x4;

static __device__ __forceinline__ unsigned short f2bf(float f) {
    unsigned u = __float_as_uint(f);
    unsigned r = (u + 0x7fffu + ((u >> 16) & 1u)) >> 16;   // RNE
    return (unsigned short)r;
}

// exact-enough GELU: A&S 7.1.26 erf (|err| < 1.5e-7), branchless, ~14 VALU
static __device__ __forceinline__ float gelu_f(float h) {
    float x  = h * 0.70710678118654752f;
    float ax = fabsf(x);
    float t  = __builtin_amdgcn_rcpf(fmaf(0.3275911f, ax, 1.0f));
    float p  = fmaf(t, 1.061405429f, -1.453152027f);
    p = fmaf(p, t, 1.421413741f);
    p = fmaf(p, t, -0.284496736f);
    p = fmaf(p, t, 0.254829592f);
    p = p * t;
    float er = 1.0f - p * __expf(-ax * ax);   // erf(|x|)
    er = copysignf(er, x);
    return 0.5f * h * (1.0f + er);
}

// ---------------------------------------------------------------------------
// Fused prep: [0,64) build order+chunkof | [64,304) convert weights |
// [304,336) copy roots | 336 zero flags.   One dispatch.
// ---------------------------------------------------------------------------
__global__ __launch_bounds__(256) void prep_all(
    const float* __restrict__ root, const float* __restrict__ W1,
    const float* __restrict__ W2, const int* __restrict__ types,
    float* __restrict__ buf,
    unsigned short* __restrict__ W1F, unsigned short* __restrict__ W2F,
    unsigned short* __restrict__ order, unsigned char* __restrict__ chunkof,
    unsigned int* __restrict__ flags)
{
    int bid = blockIdx.x, tid = threadIdx.x;
    if (bid < LL) {
        int l = bid;
        __shared__ int cnt[5], cur[5];
        if (tid < 5) cnt[tid] = 0;
        __syncthreads();
        for (int s = tid; s < PAD16; s += 256) order[l*PAD16 + s] = 0xFFFFu;
        for (int m = tid; m < MM; m += 256) {
            int t = types[l*MM + m];
            int e = (t >= TT) ? TT : t;
            atomicAdd(&cnt[e], 1);
        }
        __syncthreads();
        if (tid == 0) {
            int off = 0;
            for (int e = 0; e < 5; e++) { cur[e] = off; off += ((cnt[e] + NBK - 1)/NBK)*NBK; }
        }
        __syncthreads();
        for (int m = tid; m < MM; m += 256) {
            int t = types[l*MM + m];
            int e = (t >= TT) ? TT : t;
            int pos = atomicAdd(&cur[e], 1);
            order[l*PAD16 + pos] = (unsigned short)m;
            chunkof[l*MM + m] = (unsigned char)(pos >> 4);
        }
    } else if (bid < LL + 240) {
        int t0 = (bid - LL)*256 + tid;
        if (t0 < 5*16*8*64) {
            int lane = t0 & 63;
            int kk = (t0 >> 6) & 7;
            int nt = (t0 >> 9) & 15;
            int e  = t0 >> 13;
            int n  = nt*16 + (lane & 15);
            int k0 = kk*32 + (lane >> 4)*8;
            unsigned short v[8];
            #pragma unroll
            for (int j = 0; j < 8; j++) v[j] = f2bf(W1[(e*256 + k0 + j)*256 + n]);
            *(short8v*)&W1F[t0*8] = *(short8v*)v;
        } else {
            int t = t0 - 5*16*8*64;   // < 20480
            int lane = t & 63;
            int kk = (t >> 6) & 7;
            int nt = (t >> 9) & 7;
            int e  = t >> 12;
            int n  = nt*16 + (lane & 15);
            int k0 = kk*32 + (lane >> 4)*8;
            unsigned short v[8];
            #pragma unroll
            for (int j = 0; j < 8; j++) v[j] = f2bf(W2[(e*256 + k0 + j)*128 + n]);
            *(short8v*)&W2F[t*8] = *(short8v*)v;
        }
    } else if (bid < LL + 240 + 32) {
        int idx = (bid - (LL + 240))*256 + tid;   // 0..8191
        const f32x4* r4 = (const f32x4*)root;
        f32x4* o4 = (f32x4*)buf;
        #pragma unroll
        for (int q = 0; q < 4; q++) o4[idx*4 + q] = r4[idx*4 + q];
    } else {
        for (int i = tid; i < LL*CH; i += 256) flags[i] = 0u;
    }
}

// ---------------------------------------------------------------------------
// Persistent dataflow kernel: 133 WGs x 256 threads. WG g owns chunk g of every
// level. Per-(level,chunk) ready flags; producer protocol (validated r7/r8):
// sc1 result stores -> per-wave vmcnt(0) drain -> LDS arrive counter -> 4th
// wave publishes sc1 flag. Consumer: flag snapshot carried from the PREVIOUS
// iteration's post-publish point; phase A issues row loads for confirmed-ready
// parents + fresh flag re-loads for pending ones (hidden under L1 MFMA); a
// mid-compute check issues late row loads (hidden under L2+stores); phase B
// spins only on genuine same-level parents.
// ---------------------------------------------------------------------------
__global__ __launch_bounds__(256, 1) void persist_mfma(
    const unsigned short* __restrict__ W1F, const unsigned short* __restrict__ W2F,
    const float* __restrict__ b1, const float* __restrict__ b2,
    const float* __restrict__ slots, const int* __restrict__ par,
    const int* __restrict__ types, const unsigned short* __restrict__ order,
    const unsigned char* __restrict__ chunkof,
    float* __restrict__ buf, unsigned int* __restrict__ flags)
{
    __shared__ int4 descs[LL][NBK];            // {node, p0, p1(~slot if out), etype}
    __shared__ int2 descs2[LL][NBK];           // producer flag idx per parent (-1 ready)
    __shared__ int ech[LL];
    __shared__ unsigned short axFA[8*64*8];    // A-frags of x, 8 KB
    __shared__ unsigned short axFB[8*64*8];    // double buffer, 8 KB
    __shared__ unsigned short hxF[8*64*8];     // A-frags of h, 8 KB
    __shared__ int wcnt[2];                    // per-level wave-arrive counters

    int tid = threadIdx.x;
    int wg  = blockIdx.x;

    // ---- prologue: resolve all levels' descriptors + producer flags ----
    for (int i = tid; i < LL*NBK; i += 256) {
        int l = i >> 4, s = i & 15;
        unsigned short o = order[l*PAD16 + wg*NBK + s];
        int4 d; int2 d2 = make_int2(-1, -1);
        if (o == 0xFFFFu) {
            d = make_int4(-1, 0, 0, -1);
        } else {
            int gi = l*MM + (int)o;
            int t = types[gi];
            int e = (t >= TT) ? TT : t;
            int p0 = par[2*gi];
            int p1 = (t >= TT) ? ~(t - TT) : par[2*gi + 1];
            d = make_int4((int)o, p0, p1, e);
            if (p0 >= RR) d2.x = ((p0 - RR) >> 11)*CH + (int)chunkof[p0 - RR];
            if (p1 >= RR) d2.y = ((p1 - RR) >> 11)*CH + (int)chunkof[p1 - RR];
        }
        descs[l][s] = d;
        descs2[l][s] = d2;
    }
    if (tid == 0) { wcnt[0] = 0; wcnt[1] = 0; }
    __syncthreads();
    for (int i = tid; i < LL; i += 256) ech[i] = descs[i][0].w;
    __syncthreads();

    int w  = tid >> 6;    // wave 0..3
    int lq = tid & 63;    // lane
    int m_own  = tid >> 4;   // row this thread gathers
    int seg_own = tid & 15;  // 16-float segment

    #define RESOLVE(l1, S, F, P) {                                             \
        int4 d_ = descs[l1][m_own];                                            \
        if (d_.x < 0) { P = true; S = nullptr; F = -1; }                       \
        else {                                                                 \
            P = false;                                                         \
            int2 d2_ = descs2[l1][m_own];                                      \
            if (seg_own < 8)  { S = buf + (size_t)d_.y*DD + seg_own*16;  F = d2_.x; } \
            else if (d_.z < 0){ S = slots + (size_t)(~d_.z)*DD + (seg_own-8)*16; F = -1; } \
            else              { S = buf + (size_t)d_.z*DD + (seg_own-8)*16; F = d2_.y; } \
        } }

    #define WRITE_FRAGS(AXT, V0, V1, V2, V3) {                                 \
        unsigned short tA_[8], tB_[8];                                         \
        _Pragma("unroll")                                                      \
        for (int j = 0; j < 4; j++) {                                          \
            tA_[j]   = f2bf(V0[j]); tA_[4+j] = f2bf(V1[j]);                    \
            tB_[j]   = f2bf(V2[j]); tB_[4+j] = f2bf(V3[j]);                    \
        }                                                                      \
        int k_ = seg_own*16;                                                   \
        int kk_ = k_ >> 5, ln_ = m_own + 16*((k_ >> 3) & 3);                   \
        *(short8v*)&AXT[(kk_*64 + ln_)*8] = *(short8v*)tA_;                    \
        k_ += 8; kk_ = k_ >> 5; ln_ = m_own + 16*((k_ >> 3) & 3);              \
        *(short8v*)&AXT[(kk_*64 + ln_)*8] = *(short8v*)tB_;                    \
    }

    // ---- level-0 gather (roots/slots: always ready) ----
    {
        const float* src; int fi; bool pad;
        RESOLVE(0, src, fi, pad);
        f32x4 z = (f32x4){0.f,0.f,0.f,0.f};
        f32x4 v0 = z, v1 = z, v2 = z, v3 = z;
        if (!pad) {
            const f32x4* s4 = (const f32x4*)src;
            v0 = s4[0]; v1 = s4[1]; v2 = s4[2]; v3 = s4[3];
        }
        WRITE_FRAGS(axFA, v0, v1, v2, v3);
    }
    // ---- carry init: flag snapshot for level 1 ----
    const float* srcC = nullptr; int fiC = -1; bool padC = true; unsigned fvC = 1u;
    if (LL > 1) {
        RESOLVE(1, srcC, fiC, padC);
        if (!padC && fiC >= 0)
            fvC = __hip_atomic_load(&flags[fiC], __ATOMIC_RELAXED, __HIP_MEMORY_SCOPE_AGENT);
    }
    __syncthreads();

    unsigned short* axc = axFA;
    unsigned short* axn = axFB;

    for (int l = 0; l < LL; l++) {
        bool havN = (l + 1 < LL);
        if (tid == 0) wcnt[(l + 1) & 1] = 0;   // reset other-parity counter

        // ---- phase A: row loads for ready parents; fresh flag re-load else ----
        bool pend = false; unsigned fv2 = 1u;
        f32x4 z = (f32x4){0.f,0.f,0.f,0.f};
        f32x4 v0 = z, v1 = z, v2 = z, v3 = z;
        if (havN && !padC) {
            bool ready = (fiC < 0) || (fvC != 0u);
            if (ready) {
                asm volatile("" ::: "memory");
                const f32x4* s4 = (const f32x4*)srcC;
                v0 = s4[0]; v1 = s4[1]; v2 = s4[2]; v3 = s4[3];
            } else {
                pend = true;
                fv2 = __hip_atomic_load(&flags[fiC], __ATOMIC_RELAXED, __HIP_MEMORY_SCOPE_AGENT);
            }
        }
        __builtin_amdgcn_sched_barrier(0);   // pin: loads issued before compute

        int e = ech[l];
        if (e >= 0) {
            // ---- layer 1: H = GELU(X @ W1[e] + b1[e]) ----
            f32x4 acc[4];
            #pragma unroll
            for (int c = 0; c < 4; c++) {
                float bv = b1[e*256 + w*64 + c*16 + (lq & 15)];
                acc[c] = (f32x4){bv, bv, bv, bv};
            }
            {
                const short8v* Ab = (const short8v*)axc;
                #pragma unroll
                for (int kk = 0; kk < 8; kk++) {
                    short8v a = Ab[kk*64 + lq];
                    #pragma unroll
                    for (int c = 0; c < 4; c++) {
                        int nt = w*4 + c;
                        short8v bfr = *(const short8v*)&W1F[(((e*16 + nt)*8 + kk)*64 + lq)*8];
                        acc[c] = __builtin_amdgcn_mfma_f32_16x16x32_bf16(a, bfr, acc[c], 0, 0, 0);
                    }
                }
            }
            // ---- mid-check: late flags arrived? issue row loads now (hidden) ----
            if (pend && fv2 != 0u) {
                asm volatile("" ::: "memory");
                const f32x4* s4 = (const f32x4*)srcC;
                v0 = s4[0]; v1 = s4[1]; v2 = s4[2]; v3 = s4[3];
                pend = false;
            }
            __builtin_amdgcn_sched_barrier(0);

            #pragma unroll
            for (int c = 0; c < 4; c++) {
                int nh = w*64 + c*16 + (lq & 15);
                int kk2 = nh >> 5;
                int jj  = nh & 7;
                int lhi = 16*((nh >> 3) & 3);
                #pragma unroll
                for (int r = 0; r < 4; r++) {
                    int m = (lq >> 4)*4 + r;
                    hxF[(kk2*64 + (m + lhi))*8 + jj] = f2bf(gelu_f(acc[c][r]));
                }
            }
            __syncthreads();

            // ---- layer 2: OUT = H @ W2[e] + b2[e] ----
            f32x4 acc2[2];
            #pragma unroll
            for (int c = 0; c < 2; c++) {
                float bv = b2[e*128 + w*32 + c*16 + (lq & 15)];
                acc2[c] = (f32x4){bv, bv, bv, bv};
            }
            {
                const short8v* Hb = (const short8v*)hxF;
                #pragma unroll
                for (int kk = 0; kk < 8; kk++) {
                    short8v a = Hb[kk*64 + lq];
                    #pragma unroll
                    for (int c = 0; c < 2; c++) {
                        int nt = w*2 + c;
                        short8v bfr = *(const short8v*)&W2F[(((e*8 + nt)*8 + kk)*64 + lq)*8];
                        acc2[c] = __builtin_amdgcn_mfma_f32_16x16x32_bf16(a, bfr, acc2[c], 0, 0, 0);
                    }
                }
            }
            // result rows: sc1 write-through to the coherence point
            int baserow = RR + l*MM;
            #pragma unroll
            for (int r = 0; r < 4; r++) {
                int m = (lq >> 4)*4 + r;
                int node = descs[l][m].x;
                if (node >= 0) {
                    #pragma unroll
                    for (int c = 0; c < 2; c++) {
                        int n = w*32 + c*16 + (lq & 15);
                        __hip_atomic_store(&buf[(size_t)(baserow + node)*DD + n], acc2[c][r],
                                           __ATOMIC_RELAXED, __HIP_MEMORY_SCOPE_AGENT);
                    }
                }
            }
            // per-wave drain, LDS arrive, 4th wave publishes (no barrier)
            asm volatile("s_waitcnt vmcnt(0)" ::: "memory");
            if ((tid & 63) == 0) {
                int old = atomicAdd(&wcnt[l & 1], 1);
                if (old == 3)
                    __hip_atomic_store(&flags[l*CH + wg], 1u, __ATOMIC_RELAXED,
                                       __HIP_MEMORY_SCOPE_AGENT);
            }
        }

        // ---- phase B: spin only on genuine same-level parents; write frags ----
        if (havN) {
            if (pend) {
                while (__hip_atomic_load(&flags[fiC], __ATOMIC_RELAXED,
                                         __HIP_MEMORY_SCOPE_AGENT) == 0u)
                    __builtin_amdgcn_s_sleep(1);
                asm volatile("" ::: "memory");
                const f32x4* s4 = (const f32x4*)srcC;
                v0 = s4[0]; v1 = s4[1]; v2 = s4[2]; v3 = s4[3];
            }
            WRITE_FRAGS(axn, v0, v1, v2, v3);
        }

        // ---- post-publish flag snapshot for level l+2 (carried) ----
        const float* srcN = nullptr; int fiN = -1; bool padN = true; unsigned fvN = 1u;
        if (l + 2 < LL) {
            RESOLVE(l+2, srcN, fiN, padN);
            if (!padN && fiN >= 0)
                fvN = __hip_atomic_load(&flags[fiN], __ATOMIC_RELAXED, __HIP_MEMORY_SCOPE_AGENT);
        }
        __syncthreads();
        unsigned short* t2 = axc; axc = axn; axn = t2;
        srcC = srcN; fiC = fiN; padC = padN; fvC = fvN;
    }
}

extern "C" void kernel_launch(void* const* d_in, const int* in_sizes, int n_in,
                              void* d_out, int out_size, void* d_ws, size_t ws_size,
                              hipStream_t stream) {
    const float* root  = (const float*)d_in[0];   // (1024, 128)
    const float* W1    = (const float*)d_in[1];   // (5, 256, 256)
    const float* b1    = (const float*)d_in[2];   // (5, 256)
    const float* W2    = (const float*)d_in[3];   // (5, 256, 128)
    const float* b2    = (const float*)d_in[4];   // (5, 128)
    const float* slots = (const float*)d_in[5];   // (256, 128)
    const int*   par   = (const int*)d_in[6];     // (131072, 2)
    const int*   typ   = (const int*)d_in[7];     // (131072,)
    float* out = (float*)d_out;                   // (132096, 128)

    unsigned short* W1F     = (unsigned short*)d_ws;          // 327680 shorts
    unsigned short* W2F     = W1F + 5*16*8*64*8;              // 163840 shorts
    unsigned short* order   = W2F + 5*8*8*64*8;               // 64*2128 shorts
    unsigned char*  chunkof = (unsigned char*)(order + LL*PAD16);  // 131072 B
    unsigned int*   flags   = (unsigned int*)(chunkof + LL*MM);    // 8512 u32

    // single fused prep dispatch (order/chunkof, weights, roots, flags)
    prep_all<<<LL + 240 + 32 + 1, 256, 0, stream>>>(root, W1, W2, typ, out,
                                                    W1F, W2F, order, chunkof, flags);

    // persistent dataflow sweep (co-residency guaranteed by cooperative launch)
    void* args[] = { (void*)&W1F, (void*)&W2F, (void*)&b1, (void*)&b2,
                     (void*)&slots, (void*)&par, (void*)&typ, (void*)&order,
                     (void*)&chunkof, (void*)&out, (void*)&flags };
    hipLaunchCooperativeKernel((const void*)persist_mfma, dim3(CH), dim3(256),
                               args, 0, stream);
}